// Round 1
// baseline (586.973 us; speedup 1.0000x reference)
//
#include <hip/hip_runtime.h>
#include <math.h>

#define HW (512 * 512)
#define NB 16
#define BPB 128      // blocks per batch for pixel-pass kernels
#define NTHR 256

// ---- workspace layout (in 4-byte words) ----
#define OFF_KCNT   0                     // 16*8 uint
#define OFF_TCNT   (OFF_KCNT + 128)      // 16*8 uint
#define OFF_POS    (OFF_TCNT + 128)      // 16 uint
#define OFF_NEG    (OFF_POS + 16)        // 16 uint
#define OFF_PREFIX (OFF_NEG + 16)        // 16 uint
#define OFF_KK     (OFF_PREFIX + 16)     // 16 uint
#define OFF_FALLB  (OFF_KK + 16)         // 16 uint
#define OFF_THR    (OFF_FALLB + 16)      // 16 float
#define OFF_KSUM   (OFF_THR + 16)        // 16*32 float
#define OFF_AVGS   (OFF_KSUM + 512)      // 16*32 float
#define OFF_AGGR   (OFF_AVGS + 512)      // 16*8 float
#define OFF_AK     (OFF_AGGR + 128)      // 16 float
#define OFF_BK     (OFF_AK + 16)
#define OFF_CK     (OFF_BK + 16)
#define OFF_AT     (OFF_CK + 16)
#define OFF_BT     (OFF_AT + 16)
#define OFF_CT     (OFF_BT + 16)
#define OFF_DISCR  (OFF_CT + 16)         // 16 float
#define OFF_NVAL   (OFF_DISCR + 16)      // 16 uint
#define OFF_HIST   (OFF_NVAL + 16)       // 4*16*256 uint
#define WS_WORDS   (OFF_HIST + 4 * 16 * 256)

__device__ __forceinline__ unsigned fmap(float f) {
    unsigned u = __float_as_uint(f);
    return (u & 0x80000000u) ? ~u : (u | 0x80000000u);
}
__device__ __forceinline__ float funmap(unsigned u) {
    return (u & 0x80000000u) ? __uint_as_float(u & 0x7FFFFFFFu)
                             : __uint_as_float(~u);
}

// ---------------- K1: per-batch stats + kernel-dice sums ----------------
__global__ void k_stats(const float* __restrict__ preds,
                        const int* __restrict__ text,
                        const int* __restrict__ kern,
                        const int* __restrict__ mask,
                        unsigned* __restrict__ wsu) {
    float* wsf = (float*)wsu;
    const int b = blockIdx.y;
    const int tid = threadIdx.x;
    __shared__ unsigned s_kcnt[8], s_tcnt[8];
    __shared__ float s_ksum[32];
    if (tid < 8) { s_kcnt[tid] = 0u; s_tcnt[tid] = 0u; }
    if (tid < 32) s_ksum[tid] = 0.f;
    __syncthreads();

    const int* tb = text + b * HW;
    const int* kb = kern + b * HW;
    const int* mb = mask + b * HW;
    const float* pk = preds + (size_t)(b * 6 + 1) * HW;
    const float* e0 = preds + (size_t)(b * 6 + 2) * HW;

    unsigned r_pos = 0, r_neg = 0;
    float r_ak = 0.f, r_bk = 0.f, r_ck = 0.f;

    for (int p = blockIdx.x * NTHR + tid; p < HW; p += BPB * NTHR) {
        int t = tb[p], k = kb[p], m = mb[p];
        if (k > 0 && k <= 8) {
            atomicAdd(&s_kcnt[k - 1], 1u);
            float v0 = e0[p], v1 = e0[p + HW], v2 = e0[p + 2 * HW], v3 = e0[p + 3 * HW];
            atomicAdd(&s_ksum[(k - 1) * 4 + 0], v0);
            atomicAdd(&s_ksum[(k - 1) * 4 + 1], v1);
            atomicAdd(&s_ksum[(k - 1) * 4 + 2], v2);
            atomicAdd(&s_ksum[(k - 1) * 4 + 3], v3);
        }
        if (t > 0 && t <= 8) atomicAdd(&s_tcnt[t - 1], 1u);
        bool pos = t > 0, mp = m > 0;
        if (!pos) r_neg++;
        if (pos && mp) {
            r_pos++;
            // kernel dice: samp_k = pos & mask; target ind = (k > 0)
            float sg = 1.f / (1.f + expf(-pk[p]));
            float ik = (k > 0) ? 1.f : 0.f;
            r_ak += sg * ik;
            r_bk += sg * sg;
            r_ck += ik;
        }
    }
    // wave reduce the register accumulators
    for (int o = 32; o; o >>= 1) {
        r_pos += __shfl_down(r_pos, o);
        r_neg += __shfl_down(r_neg, o);
        r_ak += __shfl_down(r_ak, o);
        r_bk += __shfl_down(r_bk, o);
        r_ck += __shfl_down(r_ck, o);
    }
    __syncthreads();
    if ((tid & 63) == 0) {
        atomicAdd(&wsu[OFF_POS + b], r_pos);
        atomicAdd(&wsu[OFF_NEG + b], r_neg);
        atomicAdd(&wsf[OFF_AK + b], r_ak);
        atomicAdd(&wsf[OFF_BK + b], r_bk);
        atomicAdd(&wsf[OFF_CK + b], r_ck);
    }
    if (tid < 8) {
        atomicAdd(&wsu[OFF_KCNT + b * 8 + tid], s_kcnt[tid]);
        atomicAdd(&wsu[OFF_TCNT + b * 8 + tid], s_tcnt[tid]);
    }
    if (tid < 32) atomicAdd(&wsf[OFF_KSUM + b * 32 + tid], s_ksum[tid]);
}

// ---------------- K2: avgs, valid, discrimination loss, OHEM setup ----------------
__global__ void k_setup(unsigned* __restrict__ wsu) {
    int b = threadIdx.x;
    if (b >= NB) return;
    float* wsf = (float*)wsu;
    float avg[8][4];
    bool valid[8];
    int nval = 0;
    for (int i = 0; i < 8; i++) {
        unsigned kc = wsu[OFF_KCNT + b * 8 + i];
        unsigned tc = wsu[OFF_TCNT + b * 8 + i];
        valid[i] = (kc > 0) && (tc > 0);
        if (valid[i]) nval++;
        float inv = 1.f / fmaxf((float)kc, 1.f);
        for (int c = 0; c < 4; c++) {
            avg[i][c] = wsf[OFF_KSUM + b * 32 + i * 4 + c] * inv;
            wsf[OFF_AVGS + b * 32 + i * 4 + c] = avg[i][c];
        }
    }
    float Lsum = 0.f;
    for (int i = 0; i < 8; i++)
        for (int j = i + 1; j < 8; j++)
            if (valid[i] && valid[j]) {
                float sq = 0.f;
                for (int c = 0; c < 4; c++) {
                    float d = avg[i][c] - avg[j][c];
                    sq += d * d;
                }
                float dd = sqrtf(sq);
                float h = fmaxf(3.0f - dd, 0.f);
                Lsum += log1pf(h * h);
            }
    wsf[OFF_DISCR + b] = (nval > 1) ? Lsum / fmaxf((float)(nval * (nval - 1)), 1.f) : 0.f;
    wsu[OFF_NVAL + b] = (unsigned)nval;

    unsigned pos = wsu[OFF_POS + b];
    unsigned neg = wsu[OFF_NEG + b];
    // (pos * 3.0f) -> int32 truncation is exact for pos <= HW
    unsigned neg_num = min(pos * 3u, neg);
    bool fb = (pos == 0u) || (neg_num == 0u);
    wsu[OFF_FALLB + b] = fb ? 1u : 0u;
    wsu[OFF_KK + b] = fb ? 0u : neg_num;
    wsu[OFF_PREFIX + b] = 0u;
}

// ---------------- K3: radix-select histogram pass ----------------
__global__ void k_hist(const float* __restrict__ preds,
                       const int* __restrict__ text,
                       unsigned* __restrict__ wsu, int pass) {
    const int b = blockIdx.y;
    const int tid = threadIdx.x;
    __shared__ unsigned h[256];
    h[tid] = 0u;
    __syncthreads();
    const unsigned prefix = wsu[OFF_PREFIX + b];
    const int shift = 24 - 8 * pass;
    const unsigned fmask = (pass == 0) ? 0u : (0xFFFFFFFFu << (shift + 8));
    const int* tb = text + b * HW;
    const float* pt = preds + (size_t)(b * 6) * HW;
    for (int p = blockIdx.x * NTHR + tid; p < HW; p += BPB * NTHR) {
        if (tb[p] == 0) {
            unsigned key = fmap(pt[p]);
            if ((key & fmask) == prefix) atomicAdd(&h[(key >> shift) & 255u], 1u);
        }
    }
    __syncthreads();
    if (h[tid]) atomicAdd(&wsu[OFF_HIST + pass * 4096 + b * 256 + tid], h[tid]);
}

// ---------------- K4: radix-select bin pick ----------------
__global__ void k_select(unsigned* __restrict__ wsu, int pass) {
    int b = threadIdx.x;
    if (b >= NB) return;
    float* wsf = (float*)wsu;
    unsigned k = wsu[OFF_KK + b];
    unsigned prefix = wsu[OFF_PREFIX + b];
    const int shift = 24 - 8 * pass;
    const unsigned* h = &wsu[OFF_HIST + pass * 4096 + b * 256];
    if (k > 0) {
        for (int bin = 255; bin >= 0; --bin) {
            unsigned c = h[bin];
            if (k <= c) { prefix |= ((unsigned)bin) << shift; break; }
            k -= c;
        }
        wsu[OFF_KK + b] = k;
        wsu[OFF_PREFIX + b] = prefix;
    }
    if (pass == 3) wsf[OFF_THR + b] = funmap(prefix);
}

// ---------------- K5: fused aggregation + OHEM text-dice pixel pass ----------------
__global__ void k_pix(const float* __restrict__ preds,
                      const int* __restrict__ text,
                      const int* __restrict__ mask,
                      unsigned* __restrict__ wsu) {
    const int b = blockIdx.y;
    const int tid = threadIdx.x;
    float* wsf = (float*)wsu;
    __shared__ float s_avg[32];
    __shared__ float s_aggr[8];
    __shared__ float s_thr;
    __shared__ unsigned s_fb;
    if (tid < 32) s_avg[tid] = wsf[OFF_AVGS + b * 32 + tid];
    if (tid < 8) s_aggr[tid] = 0.f;
    if (tid == 0) { s_thr = wsf[OFF_THR + b]; s_fb = wsu[OFF_FALLB + b]; }
    __syncthreads();
    const float thr = s_thr;
    const unsigned fb = s_fb;
    float r_at = 0.f, r_bt = 0.f, r_ct = 0.f;
    const int* tb = text + b * HW;
    const int* mb = mask + b * HW;
    const float* pt = preds + (size_t)(b * 6) * HW;
    const float* e0 = preds + (size_t)(b * 6 + 2) * HW;
    for (int p = blockIdx.x * NTHR + tid; p < HW; p += BPB * NTHR) {
        int t = tb[p];
        int m = mb[p];
        float s = pt[p];
        bool pos = t > 0;
        bool samp = fb ? (m > 0) : (((s >= thr) || pos) && (m > 0));
        if (samp) {
            float sg = 1.f / (1.f + expf(-s));
            float it = pos ? 1.f : 0.f;
            r_at += sg * it;
            r_bt += sg * sg;
            r_ct += it;
        }
        if (pos && t <= 8) {
            float d0 = e0[p] - s_avg[(t - 1) * 4 + 0];
            float d1 = e0[p + HW] - s_avg[(t - 1) * 4 + 1];
            float d2 = e0[p + 2 * HW] - s_avg[(t - 1) * 4 + 2];
            float d3 = e0[p + 3 * HW] - s_avg[(t - 1) * 4 + 3];
            float sq = d0 * d0 + d1 * d1 + d2 * d2 + d3 * d3;
            float dist = sqrtf(sq + 1e-12f) - 0.5f;
            float hp = fmaxf(dist, 0.f);
            atomicAdd(&s_aggr[t - 1], log1pf(hp * hp));
        }
    }
    for (int o = 32; o; o >>= 1) {
        r_at += __shfl_down(r_at, o);
        r_bt += __shfl_down(r_bt, o);
        r_ct += __shfl_down(r_ct, o);
    }
    __syncthreads();
    if ((tid & 63) == 0) {
        atomicAdd(&wsf[OFF_AT + b], r_at);
        atomicAdd(&wsf[OFF_BT + b], r_bt);
        atomicAdd(&wsf[OFF_CT + b], r_ct);
    }
    if (tid < 8) atomicAdd(&wsf[OFF_AGGR + b * 8 + tid], s_aggr[tid]);
}

// ---------------- K6: final assembly ----------------
__global__ void k_final(unsigned* __restrict__ wsu, float* __restrict__ out) {
    float* wsf = (float*)wsu;
    __shared__ float lt[NB], lk[NB], la[NB], ld[NB];
    int b = threadIdx.x;
    if (b < NB) {
        const float S = 1e-3f;
        float a = wsf[OFF_AT + b] + S, bb = wsf[OFF_BT + b] + S, c = wsf[OFF_CT + b] + S;
        lt[b] = 1.f - 2.f * a / (bb + c);
        a = wsf[OFF_AK + b] + S; bb = wsf[OFF_BK + b] + S; c = wsf[OFF_CK + b] + S;
        lk[b] = 1.f - 2.f * a / (bb + c);
        int nval = (int)wsu[OFF_NVAL + b];
        float sum = 0.f;
        for (int i = 0; i < 8; i++) {
            unsigned kc = wsu[OFF_KCNT + b * 8 + i];
            unsigned tc = wsu[OFF_TCNT + b * 8 + i];
            if (kc > 0 && tc > 0)
                sum += wsf[OFF_AGGR + b * 8 + i] / fmaxf((float)tc, 1.f);
        }
        la[b] = (nval > 0) ? sum / fmaxf((float)nval, 1.f) : 0.f;
        ld[b] = wsf[OFF_DISCR + b];
    }
    __syncthreads();
    if (b == 0) {
        float st = 0, sk = 0, sa = 0, sd = 0;
        for (int i = 0; i < NB; i++) { st += lt[i]; sk += lk[i]; sa += la[i]; sd += ld[i]; }
        out[0] = st / NB;
        out[1] = 0.5f * sk / NB;    // ALPHA
        out[2] = 0.25f * sa / NB;   // BETA
        out[3] = 0.25f * sd / NB;   // BETA
    }
}

extern "C" void kernel_launch(void* const* d_in, const int* in_sizes, int n_in,
                              void* d_out, int out_size, void* d_ws, size_t ws_size,
                              hipStream_t stream) {
    const float* preds = (const float*)d_in[0];
    const int* text = (const int*)d_in[1];
    const int* kern = (const int*)d_in[2];
    const int* mask = (const int*)d_in[3];
    unsigned* wsu = (unsigned*)d_ws;
    float* out = (float*)d_out;

    hipMemsetAsync(d_ws, 0, (size_t)WS_WORDS * 4, stream);

    dim3 grid(BPB, NB);
    k_stats<<<grid, NTHR, 0, stream>>>(preds, text, kern, mask, wsu);
    k_setup<<<1, 64, 0, stream>>>(wsu);
    for (int pass = 0; pass < 4; pass++) {
        k_hist<<<grid, NTHR, 0, stream>>>(preds, text, wsu, pass);
        k_select<<<1, 64, 0, stream>>>(wsu, pass);
    }
    k_pix<<<grid, NTHR, 0, stream>>>(preds, text, mask, wsu);
    k_final<<<1, 64, 0, stream>>>(wsu, out);
}

// Round 2
// 537.282 us; speedup vs baseline: 1.0925x; 1.0925x over previous
//
#include <hip/hip_runtime.h>
#include <math.h>

#define HW (512 * 512)
#define NB 16
#define NTHR 256
#define BPB 64   // blocks per batch; iters = HW/(BPB*NTHR*4) = 4

// ---- workspace layout (4-byte words) ----
// zeroed region:
#define OFF_KCNT   0                      // f [16][8]
#define OFF_TCNT   (OFF_KCNT + 128)      // f [16][8]
#define OFF_KSUM   (OFF_TCNT + 128)      // f [16][32]
#define OFF_POS    (OFF_KSUM + 512)      // f [16]
#define OFF_AK     (OFF_POS + 16)
#define OFF_BK     (OFF_AK + 16)
#define OFF_CK     (OFF_BK + 16)
#define OFF_AT     (OFF_CK + 16)
#define OFF_BT     (OFF_AT + 16)
#define OFF_CT     (OFF_BT + 16)
#define OFF_AGGR   (OFF_CT + 16)         // f [16] (w-weighted lg sums)
#define OFF_NEGC   (OFF_AGGR + 16)       // u [16]
#define OFF_HISTFB (OFF_NEGC + 16)       // u [4][16][256] fallback hists
#define ZERO_WORDS (OFF_HISTFB + 4 * 16 * 256)
// non-zeroed region:
#define OFF_TBL    ZERO_WORDS            // f [16][9][5]: rows 0..8 = {a0..a3, w}
#define OFF_THR    (OFF_TBL + 16 * 45)   // f [16]
#define OFF_FB     (OFF_THR + 16)        // u [16]
#define OFF_NVAL   (OFF_FB + 16)         // u [16]
#define OFF_DISCR  (OFF_NVAL + 16)       // f [16]
#define OFF_PREFIX (OFF_DISCR + 16)      // u [16] (fallback select state)
#define OFF_KKC    (OFF_PREFIX + 16)     // u [16]
#define OFF_KEYS   (OFF_KKC + 16)        // u [16][HW] compacted neg keys
#define WS_FULL_BYTES ((size_t)(OFF_KEYS + NB * HW) * 4)

__device__ __forceinline__ unsigned fmap(float f) {
    unsigned u = __float_as_uint(f);
    return (u & 0x80000000u) ? ~u : (u | 0x80000000u);
}
__device__ __forceinline__ float funmap(unsigned u) {
    return (u & 0x80000000u) ? __uint_as_float(u & 0x7FFFFFFFu)
                             : __uint_as_float(~u);
}
__device__ __forceinline__ float wred(float x) {
#pragma unroll
    for (int o = 32; o; o >>= 1) x += __shfl_xor(x, o);
    return x;
}

// ---------------- K1: stats + kernel-dice + negative-key compaction ----------------
__global__ void k_stats(const float* __restrict__ preds,
                        const int* __restrict__ text,
                        const int* __restrict__ kern,
                        const int* __restrict__ mask,
                        unsigned* __restrict__ wsu, int do_compact) {
    float* wsf = (float*)wsu;
    const int b = blockIdx.y;
    const int tid = threadIdx.x;
    const int lane = tid & 63;
    __shared__ float sacc[52];
    if (tid < 52) sacc[tid] = 0.f;
    __syncthreads();

    const int* tb = text + b * HW;
    const int* kb = kern + b * HW;
    const int* mb = mask + b * HW;
    const float* p0 = preds + (size_t)(b * 6 + 0) * HW;
    const float* p1 = preds + (size_t)(b * 6 + 1) * HW;
    const float* e0 = preds + (size_t)(b * 6 + 2) * HW;
    const float* e1 = e0 + HW;
    const float* e2 = e0 + 2 * HW;
    const float* e3 = e0 + 3 * HW;
    unsigned* keys = wsu + OFF_KEYS + (size_t)b * HW;

    float kc[8], tc[8], ks0[8], ks1[8], ks2[8], ks3[8];
#pragma unroll
    for (int i = 0; i < 8; i++) { kc[i] = tc[i] = ks0[i] = ks1[i] = ks2[i] = ks3[i] = 0.f; }
    float r_pos = 0.f, r_ak = 0.f, r_bk = 0.f, r_ck = 0.f;

    for (int base = (blockIdx.x * NTHR + tid) * 4; base < HW; base += BPB * NTHR * 4) {
        int4 t4 = *(const int4*)(tb + base);
        int4 k4 = *(const int4*)(kb + base);
        int4 m4 = *(const int4*)(mb + base);
        float4 s4 = *(const float4*)(p0 + base);
        float4 q4 = *(const float4*)(p1 + base);
        float4 a4 = *(const float4*)(e0 + base);
        float4 b4 = *(const float4*)(e1 + base);
        float4 c4 = *(const float4*)(e2 + base);
        float4 d4 = *(const float4*)(e3 + base);
        int tv[4] = {t4.x, t4.y, t4.z, t4.w};
        int kv[4] = {k4.x, k4.y, k4.z, k4.w};
        int mv[4] = {m4.x, m4.y, m4.z, m4.w};
        float sv[4] = {s4.x, s4.y, s4.z, s4.w};
        float qv[4] = {q4.x, q4.y, q4.z, q4.w};
        float av[4] = {a4.x, a4.y, a4.z, a4.w};
        float bv[4] = {b4.x, b4.y, b4.z, b4.w};
        float cv[4] = {c4.x, c4.y, c4.z, c4.w};
        float dv[4] = {d4.x, d4.y, d4.z, d4.w};
        unsigned key4[4];
        int ng4[4];
#pragma unroll
        for (int j = 0; j < 4; j++) {
            int t = tv[j], k = kv[j], m = mv[j];
            bool pos = t > 0, mp = m > 0;
            float sm = (pos && mp) ? 1.f : 0.f;
            float sg = 1.f / (1.f + expf(-qv[j]));
            float ik = (k > 0) ? 1.f : 0.f;
            r_pos += sm;
            r_ak += sm * sg * ik;
            r_bk += sm * sg * sg;
            r_ck += sm * ik;
#pragma unroll
            for (int i = 0; i < 8; i++) {
                float hk = (k == i + 1) ? 1.f : 0.f;
                kc[i] += hk;
                ks0[i] += hk * av[j];
                ks1[i] += hk * bv[j];
                ks2[i] += hk * cv[j];
                ks3[i] += hk * dv[j];
                tc[i] += (t == i + 1) ? 1.f : 0.f;
            }
            ng4[j] = (t == 0) ? 1 : 0;
            key4[j] = fmap(sv[j]);
        }
        // compact negative keys: wave scan of per-thread count
        unsigned nn = (unsigned)(ng4[0] + ng4[1] + ng4[2] + ng4[3]);
        unsigned v = nn;
#pragma unroll
        for (int off = 1; off < 64; off <<= 1) {
            unsigned u = __shfl_up(v, off);
            if (lane >= off) v += u;
        }
        unsigned tot = __shfl(v, 63);
        unsigned bs = 0;
        if (lane == 63 && tot) bs = atomicAdd(&wsu[OFF_NEGC + b], tot);
        bs = __shfl(bs, 63);
        if (do_compact && tot) {
            unsigned o = bs + v - nn;
            if (ng4[0]) { keys[o] = key4[0]; o++; }
            if (ng4[1]) { keys[o] = key4[1]; o++; }
            if (ng4[2]) { keys[o] = key4[2]; o++; }
            if (ng4[3]) { keys[o] = key4[3]; o++; }
        }
    }

    // wave reduce -> LDS -> global
#pragma unroll
    for (int i = 0; i < 8; i++) { float v = wred(kc[i]); if (lane == 0) atomicAdd(&sacc[i], v); }
#pragma unroll
    for (int i = 0; i < 8; i++) { float v = wred(tc[i]); if (lane == 0) atomicAdd(&sacc[8 + i], v); }
#pragma unroll
    for (int i = 0; i < 8; i++) {
        float v = wred(ks0[i]); if (lane == 0) atomicAdd(&sacc[16 + i * 4 + 0], v);
        v = wred(ks1[i]); if (lane == 0) atomicAdd(&sacc[16 + i * 4 + 1], v);
        v = wred(ks2[i]); if (lane == 0) atomicAdd(&sacc[16 + i * 4 + 2], v);
        v = wred(ks3[i]); if (lane == 0) atomicAdd(&sacc[16 + i * 4 + 3], v);
    }
    {
        float v = wred(r_pos); if (lane == 0) atomicAdd(&sacc[48], v);
        v = wred(r_ak); if (lane == 0) atomicAdd(&sacc[49], v);
        v = wred(r_bk); if (lane == 0) atomicAdd(&sacc[50], v);
        v = wred(r_ck); if (lane == 0) atomicAdd(&sacc[51], v);
    }
    __syncthreads();
    if (tid < 52) {
        float v = sacc[tid];
        int gi;
        if (tid < 8) gi = OFF_KCNT + b * 8 + tid;
        else if (tid < 16) gi = OFF_TCNT + b * 8 + (tid - 8);
        else if (tid < 48) gi = OFF_KSUM + b * 32 + (tid - 16);
        else if (tid == 48) gi = OFF_POS + b;
        else if (tid == 49) gi = OFF_AK + b;
        else if (tid == 50) gi = OFF_BK + b;
        else gi = OFF_CK + b;
        atomicAdd(&wsf[gi], v);
    }
}

// ---------------- K2: setup (avgs, w, discr, OHEM params) + 4-pass radix select ----------------
__global__ void k_sel(unsigned* __restrict__ wsu, int do_select) {
    float* wsf = (float*)wsu;
    const int b = blockIdx.x;
    const int tid = threadIdx.x;
    __shared__ float s_avg[8][4];
    __shared__ float s_w[8];
    __shared__ int s_valid[8];
    __shared__ unsigned s_hist[256];
    __shared__ unsigned s_kk, s_prefix;

    if (tid < 8) {
        float kcf = wsf[OFF_KCNT + b * 8 + tid];
        float tcf = wsf[OFF_TCNT + b * 8 + tid];
        int valid = (kcf > 0.f && tcf > 0.f) ? 1 : 0;
        float inv = 1.f / fmaxf(kcf, 1.f);
        float w = valid ? 1.f / fmaxf(tcf, 1.f) : 0.f;
#pragma unroll
        for (int c = 0; c < 4; c++) {
            float a = wsf[OFF_KSUM + b * 32 + tid * 4 + c] * inv;
            s_avg[tid][c] = a;
            wsf[OFF_TBL + b * 45 + (tid + 1) * 5 + c] = a;
        }
        s_w[tid] = w;
        s_valid[tid] = valid;
        wsf[OFF_TBL + b * 45 + (tid + 1) * 5 + 4] = w;
    }
    if (tid < 5) wsf[OFF_TBL + b * 45 + tid] = 0.f;  // background row
    __syncthreads();
    if (tid == 0) {
        int nval = 0;
        for (int i = 0; i < 8; i++) nval += s_valid[i];
        float L = 0.f;
        for (int i = 0; i < 8; i++)
            for (int j = i + 1; j < 8; j++)
                if (s_valid[i] && s_valid[j]) {
                    float sq = 0.f;
                    for (int c = 0; c < 4; c++) {
                        float d = s_avg[i][c] - s_avg[j][c];
                        sq += d * d;
                    }
                    float h = fmaxf(3.0f - sqrtf(sq), 0.f);
                    L += log1pf(h * h);
                }
        wsf[OFF_DISCR + b] = (nval > 1) ? L / fmaxf((float)(nval * (nval - 1)), 1.f) : 0.f;
        wsu[OFF_NVAL + b] = (unsigned)nval;
        unsigned pos = (unsigned)wsf[OFF_POS + b];
        unsigned neg = wsu[OFF_NEGC + b];
        unsigned nn = min(pos * 3u, neg);
        int fb = (pos == 0u || nn == 0u) ? 1 : 0;
        wsu[OFF_FB + b] = (unsigned)fb;
        s_kk = fb ? 0u : nn;
        s_prefix = 0u;
        wsu[OFF_KKC + b] = fb ? 0u : nn;   // fallback path state
        wsu[OFF_PREFIX + b] = 0u;
        wsf[OFF_THR + b] = 0.f;
    }
    __syncthreads();
    if (!do_select) return;
    if (s_kk == 0u) return;
    const unsigned count = wsu[OFF_NEGC + b];
    const unsigned* keys = wsu + OFF_KEYS + (size_t)b * HW;
    unsigned prefix = 0u, kk = s_kk;
    for (int pass = 0; pass < 4; pass++) {
        const int shift = 24 - 8 * pass;
        const unsigned fmask = (pass == 0) ? 0u : (0xFFFFFFFFu << (shift + 8));
        s_hist[tid] = 0u;
        __syncthreads();
        for (unsigned i = tid; i < count; i += NTHR) {
            unsigned key = keys[i];
            if ((key & fmask) == prefix) atomicAdd(&s_hist[(key >> shift) & 255u], 1u);
        }
        __syncthreads();
        if (tid == 0) {
            unsigned k2 = kk;
            for (int bin = 255; bin >= 0; --bin) {
                unsigned c = s_hist[bin];
                if (k2 <= c) { s_prefix = prefix | (((unsigned)bin) << shift); s_kk = k2; break; }
                k2 -= c;
            }
        }
        __syncthreads();
        prefix = s_prefix;
        kk = s_kk;
    }
    if (tid == 0) wsf[OFF_THR + b] = funmap(prefix);
}

// ---------------- fallback radix select over raw data (only if ws too small) ----------------
__global__ void k_hist(const float* __restrict__ preds, const int* __restrict__ text,
                       unsigned* __restrict__ wsu, int pass) {
    const int b = blockIdx.y;
    const int tid = threadIdx.x;
    __shared__ unsigned h[256];
    h[tid] = 0u;
    __syncthreads();
    const unsigned prefix = wsu[OFF_PREFIX + b];
    const int shift = 24 - 8 * pass;
    const unsigned fmask = (pass == 0) ? 0u : (0xFFFFFFFFu << (shift + 8));
    const int* tb = text + b * HW;
    const float* pt = preds + (size_t)(b * 6) * HW;
    for (int p = blockIdx.x * NTHR + tid; p < HW; p += gridDim.x * NTHR) {
        if (tb[p] == 0) {
            unsigned key = fmap(pt[p]);
            if ((key & fmask) == prefix) atomicAdd(&h[(key >> shift) & 255u], 1u);
        }
    }
    __syncthreads();
    if (h[tid]) atomicAdd(&wsu[OFF_HISTFB + pass * 4096 + b * 256 + tid], h[tid]);
}
__global__ void k_select(unsigned* __restrict__ wsu, int pass) {
    int b = threadIdx.x;
    if (b >= NB) return;
    float* wsf = (float*)wsu;
    unsigned k = wsu[OFF_KKC + b];
    unsigned prefix = wsu[OFF_PREFIX + b];
    const int shift = 24 - 8 * pass;
    const unsigned* h = &wsu[OFF_HISTFB + pass * 4096 + b * 256];
    if (k > 0) {
        for (int bin = 255; bin >= 0; --bin) {
            unsigned c = h[bin];
            if (k <= c) { prefix |= ((unsigned)bin) << shift; break; }
            k -= c;
        }
        wsu[OFF_KKC + b] = k;
        wsu[OFF_PREFIX + b] = prefix;
    }
    if (pass == 3) wsf[OFF_THR + b] = funmap(prefix);
}

// ---------------- K3: fused aggregation + OHEM text-dice pixel pass ----------------
__global__ void k_pix(const float* __restrict__ preds,
                      const int* __restrict__ text,
                      const int* __restrict__ mask,
                      unsigned* __restrict__ wsu) {
    float* wsf = (float*)wsu;
    const int b = blockIdx.y;
    const int tid = threadIdx.x;
    const int lane = tid & 63;
    __shared__ float stbl[45];
    __shared__ float sred[4];
    __shared__ float sthr;
    __shared__ unsigned sfb;
    if (tid < 45) stbl[tid] = wsf[OFF_TBL + b * 45 + tid];
    if (tid < 4) sred[tid] = 0.f;
    if (tid == 0) { sthr = wsf[OFF_THR + b]; sfb = wsu[OFF_FB + b]; }
    __syncthreads();
    const float thr = sthr;
    const bool fb = sfb != 0u;
    float r_at = 0.f, r_bt = 0.f, r_ct = 0.f, r_ag = 0.f;
    const int* tb = text + b * HW;
    const int* mb = mask + b * HW;
    const float* p0 = preds + (size_t)(b * 6) * HW;
    const float* e0 = preds + (size_t)(b * 6 + 2) * HW;
    const float* e1 = e0 + HW;
    const float* e2 = e0 + 2 * HW;
    const float* e3 = e0 + 3 * HW;
    for (int base = (blockIdx.x * NTHR + tid) * 4; base < HW; base += BPB * NTHR * 4) {
        int4 t4 = *(const int4*)(tb + base);
        int4 m4 = *(const int4*)(mb + base);
        float4 s4 = *(const float4*)(p0 + base);
        float4 a4 = *(const float4*)(e0 + base);
        float4 b4 = *(const float4*)(e1 + base);
        float4 c4 = *(const float4*)(e2 + base);
        float4 d4 = *(const float4*)(e3 + base);
        int tv[4] = {t4.x, t4.y, t4.z, t4.w};
        int mv[4] = {m4.x, m4.y, m4.z, m4.w};
        float sv[4] = {s4.x, s4.y, s4.z, s4.w};
        float av[4] = {a4.x, a4.y, a4.z, a4.w};
        float bv[4] = {b4.x, b4.y, b4.z, b4.w};
        float cv[4] = {c4.x, c4.y, c4.z, c4.w};
        float dv[4] = {d4.x, d4.y, d4.z, d4.w};
#pragma unroll
        for (int j = 0; j < 4; j++) {
            int t = tv[j], m = mv[j];
            float s = sv[j];
            bool pos = t > 0;
            bool samp = fb ? (m > 0) : (((s >= thr) || pos) && (m > 0));
            float sg = 1.f / (1.f + expf(-s));
            float smf = samp ? 1.f : 0.f;
            float it = pos ? 1.f : 0.f;
            r_at += smf * sg * it;
            r_bt += smf * sg * sg;
            r_ct += smf * it;
            int ti = min(t, 8);
            int tb5 = ti * 5;
            float d0 = av[j] - stbl[tb5 + 0];
            float d1 = bv[j] - stbl[tb5 + 1];
            float d2 = cv[j] - stbl[tb5 + 2];
            float d3 = dv[j] - stbl[tb5 + 3];
            float w = stbl[tb5 + 4];
            float sq = d0 * d0 + d1 * d1 + d2 * d2 + d3 * d3;
            float dist = sqrtf(sq + 1e-12f) - 0.5f;
            float hp = fmaxf(dist, 0.f);
            r_ag += w * log1pf(hp * hp);
        }
    }
    {
        float v = wred(r_at); if (lane == 0) atomicAdd(&sred[0], v);
        v = wred(r_bt); if (lane == 0) atomicAdd(&sred[1], v);
        v = wred(r_ct); if (lane == 0) atomicAdd(&sred[2], v);
        v = wred(r_ag); if (lane == 0) atomicAdd(&sred[3], v);
    }
    __syncthreads();
    if (tid < 4) {
        int gi = (tid == 0) ? (OFF_AT + b) : (tid == 1) ? (OFF_BT + b)
               : (tid == 2) ? (OFF_CT + b) : (OFF_AGGR + b);
        atomicAdd(&wsf[gi], sred[tid]);
    }
}

// ---------------- K4: final assembly ----------------
__global__ void k_final(unsigned* __restrict__ wsu, float* __restrict__ out) {
    float* wsf = (float*)wsu;
    __shared__ float lt[NB], lk[NB], la[NB], ld[NB];
    int b = threadIdx.x;
    if (b < NB) {
        const float S = 1e-3f;
        float a = wsf[OFF_AT + b] + S, bb = wsf[OFF_BT + b] + S, c = wsf[OFF_CT + b] + S;
        lt[b] = 1.f - 2.f * a / (bb + c);
        a = wsf[OFF_AK + b] + S; bb = wsf[OFF_BK + b] + S; c = wsf[OFF_CK + b] + S;
        lk[b] = 1.f - 2.f * a / (bb + c);
        int nval = (int)wsu[OFF_NVAL + b];
        la[b] = (nval > 0) ? wsf[OFF_AGGR + b] / fmaxf((float)nval, 1.f) : 0.f;
        ld[b] = wsf[OFF_DISCR + b];
    }
    __syncthreads();
    if (b == 0) {
        float st = 0, sk = 0, sa = 0, sd = 0;
        for (int i = 0; i < NB; i++) { st += lt[i]; sk += lk[i]; sa += la[i]; sd += ld[i]; }
        out[0] = st / NB;
        out[1] = 0.5f * sk / NB;
        out[2] = 0.25f * sa / NB;
        out[3] = 0.25f * sd / NB;
    }
}

extern "C" void kernel_launch(void* const* d_in, const int* in_sizes, int n_in,
                              void* d_out, int out_size, void* d_ws, size_t ws_size,
                              hipStream_t stream) {
    const float* preds = (const float*)d_in[0];
    const int* text = (const int*)d_in[1];
    const int* kern = (const int*)d_in[2];
    const int* mask = (const int*)d_in[3];
    unsigned* wsu = (unsigned*)d_ws;
    float* out = (float*)d_out;

    const int do_compact = (ws_size >= WS_FULL_BYTES) ? 1 : 0;

    hipMemsetAsync(d_ws, 0, (size_t)ZERO_WORDS * 4, stream);

    dim3 grid(BPB, NB);
    k_stats<<<grid, NTHR, 0, stream>>>(preds, text, kern, mask, wsu, do_compact);
    k_sel<<<NB, NTHR, 0, stream>>>(wsu, do_compact);
    if (!do_compact) {
        dim3 hgrid(128, NB);
        for (int pass = 0; pass < 4; pass++) {
            k_hist<<<hgrid, NTHR, 0, stream>>>(preds, text, wsu, pass);
            k_select<<<1, 64, 0, stream>>>(wsu, pass);
        }
    }
    k_pix<<<grid, NTHR, 0, stream>>>(preds, text, mask, wsu);
    k_final<<<1, 64, 0, stream>>>(wsu, out);
}